// Round 7
// baseline (89.197 us; speedup 1.0000x reference)
//
#include <hip/hip_runtime.h>
#include <math.h>
#include <stdint.h>

constexpr int B = 1024;
constexpr int IN = 512;   // layer1 feature dim, layer2 output dim
constexpr int HID = 256;  // layer1 output dim, layer2 feature dim

typedef _Float16 h2 __attribute__((ext_vector_type(2)));

__device__ __forceinline__ h2 asb(uint32_t v) { return __builtin_bit_cast(h2, v); }
// llvm.minnum -> IEEE minNum: min(x, qNaN) = x. Codes rely on this.
__device__ __forceinline__ h2 pkmin(h2 a, h2 b) { return __builtin_elementwise_min(a, b); }

__device__ __forceinline__ float gscore(float l, float u) {
    float uc = fminf(fmaxf(u, 1e-10f), 1.0f);
    return l - logf(-logf(uc));
}
// true -> argmax index 1 -> "max" node (strict >, matches jnp.argmax tie->0)
__device__ __forceinline__ bool rowmax(const float* __restrict__ lg,
                                       const float* __restrict__ uu, int r) {
    return gscore(lg[2 * r + 1], uu[2 * r + 1]) > gscore(lg[2 * r], uu[2 * r]);
}

__device__ __forceinline__ uint32_t code2(int m_lo, int m_hi, uint32_t s) {
    return (m_lo ? s : 0xFFFFu) | ((m_hi ? s : 0xFFFFu) << 16);
}

// Build: xh (x packed to f16 pairs), n-code tables (uint4 = 8 j per entry),
// sign tables. Code per (row, j): masked -> rowsign (0x0000 min / 0x8000 max;
// x>=0 so x|0x8000 == -x exactly), unmasked -> 0xFFFF (qNaN, ignored by minNum).
// n layout: [ot][jc][lane] uint4, ot = row>>6, lane = row&63, jc = j>>3.
__global__ __launch_bounds__(256) void prep_kernel(
    const float* __restrict__ x,
    const float* __restrict__ lg1, const float* __restrict__ u1,
    const float* __restrict__ lg2, const float* __restrict__ u2,
    const int* __restrict__ m1, const int* __restrict__ m2,
    uint32_t* __restrict__ xh, uint4* __restrict__ n1, uint4* __restrict__ n2,
    uint16_t* __restrict__ sgn1, uint16_t* __restrict__ sgn2)
{
    int idx = blockIdx.x * 256 + threadIdx.x;
    constexpr int NXH = B * IN / 2;     // 262144
    constexpr int NN1 = HID * (IN / 8); // 16384: i in [0,256), jc in [0,64)
    if (idx < NXH) {
        float2 v = reinterpret_cast<const float2*>(x)[idx];
        h2 hv; hv.x = (_Float16)v.x; hv.y = (_Float16)v.y;
        xh[idx] = __builtin_bit_cast(uint32_t, hv);
    } else if (idx < NXH + NN1) {
        int e = idx - NXH;
        int i = e & (HID - 1);
        int jc = e >> 8;                 // 0..63
        uint32_t s = rowmax(lg1, u1, i) ? 0x8000u : 0u;
        const int4* mp = reinterpret_cast<const int4*>(m1 + (size_t)i * IN + 8 * jc);
        int4 ma = mp[0], mb = mp[1];
        uint4 n;
        n.x = code2(ma.x, ma.y, s);
        n.y = code2(ma.z, ma.w, s);
        n.z = code2(mb.x, mb.y, s);
        n.w = code2(mb.z, mb.w, s);
        n1[(((i >> 6) * 64) + jc) * 64 + (i & 63)] = n;
        if (jc == 0) sgn1[i] = (uint16_t)s;
    } else {
        int e = idx - NXH - NN1;         // o in [0,512), jc in [0,32)
        int o = e & (IN - 1);
        int jc = e >> 9;                 // 0..31
        uint32_t s = rowmax(lg2, u2, o) ? 0x8000u : 0u;
        const int4* mp = reinterpret_cast<const int4*>(m2 + (size_t)o * HID + 8 * jc);
        int4 ma = mp[0], mb = mp[1];
        uint4 n;
        n.x = code2(ma.x, ma.y, s);
        n.y = code2(ma.z, ma.w, s);
        n.z = code2(mb.x, mb.y, s);
        n.w = code2(mb.z, mb.w, s);
        n2[(((o >> 6) * 32) + jc) * 64 + (o & 63)] = n;
        if (jc == 0) sgn2[o] = (uint16_t)s;
    }
}

// One layer, full-J reduction. 256-thread blocks (4 waves), no LDS.
// Lanes span 64 output rows (coalesced n-loads/stores). Each wave owns R
// consecutive batch rows; wave id is readfirstlane'd so the batch base is
// compiler-provably uniform -> x-row loads ride the scalar pipe (SMEM).
// Inner loop: 1 VMEM + R SMEM + 8R VALU per 16R elements; 2R min-chains.
// JW = J/8 (uint4 steps), OD = output rows, R = batch rows per wave.
template <int JW, int OD, int R, bool OUTF32>
__global__ __launch_bounds__(256) void layer_kernel(
    const uint32_t* __restrict__ xin,  // [B][J/2] f16-pair words
    const uint4* __restrict__ nt,      // [OD/64][JW][64]
    const uint16_t* __restrict__ sgn,  // [OD]
    void* __restrict__ outp)           // f16 [B][OD] or f32 [B][OD]
{
    constexpr int OT = OD / 64;
    int bx = blockIdx.x;
    int ot = bx % OT;
    int btile = bx / OT;               // B/(4R) tiles
    int tid = threadIdx.x;
    int lane = tid & 63;
    int wv = __builtin_amdgcn_readfirstlane(tid >> 6);  // uniform wave id
    int o = (ot << 6) + lane;
    int b0 = btile * (4 * R) + wv * R; // uniform batch-row base

    uint32_t s = (uint32_t)sgn[o];
    uint32_t sini = s ? 0u : 0x3C003C00u;   // max-row -> 0.0 (negated dom), min-row -> 1.0
    h2 acc[2 * R];
#pragma unroll
    for (int k = 0; k < 2 * R; ++k) acc[k] = asb(sini);

    const uint4* np = nt + (size_t)ot * (JW * 64) + lane;
    const uint4* xr[R];
#pragma unroll
    for (int r = 0; r < R; ++r)
        xr[r] = (const uint4*)(xin + (size_t)(b0 + r) * (JW * 4));  // uniform

    if (R == 2) {
#pragma unroll 8
        for (int jc = 0; jc < JW; ++jc) {
            uint4 n = np[jc * 64];
#pragma unroll
            for (int r = 0; r < R; ++r) {
                uint4 xv = xr[r][jc];
                acc[2 * r]     = pkmin(acc[2 * r],     asb(xv.x | n.x));
                acc[2 * r + 1] = pkmin(acc[2 * r + 1], asb(xv.y | n.y));
                acc[2 * r]     = pkmin(acc[2 * r],     asb(xv.z | n.z));
                acc[2 * r + 1] = pkmin(acc[2 * r + 1], asb(xv.w | n.w));
            }
        }
    } else {
#pragma unroll 4
        for (int jc = 0; jc < JW; ++jc) {
            uint4 n = np[jc * 64];
#pragma unroll
            for (int r = 0; r < R; ++r) {
                uint4 xv = xr[r][jc];
                acc[2 * r]     = pkmin(acc[2 * r],     asb(xv.x | n.x));
                acc[2 * r + 1] = pkmin(acc[2 * r + 1], asb(xv.y | n.y));
                acc[2 * r]     = pkmin(acc[2 * r],     asb(xv.z | n.z));
                acc[2 * r + 1] = pkmin(acc[2 * r + 1], asb(xv.w | n.w));
            }
        }
    }

#pragma unroll
    for (int r = 0; r < R; ++r) {
        h2 c = pkmin(acc[2 * r], acc[2 * r + 1]);
        _Float16 v = c.x < c.y ? c.x : c.y;    // accumulators are never NaN
        uint16_t vb = (uint16_t)(__builtin_bit_cast(uint16_t, v) ^ (uint16_t)s);
        if (OUTF32) {
            ((float*)outp)[(size_t)(b0 + r) * OD + o] =
                (float)__builtin_bit_cast(_Float16, vb);
        } else {
            ((uint16_t*)outp)[(size_t)(b0 + r) * OD + o] = vb;
        }
    }
}

extern "C" void kernel_launch(void* const* d_in, const int* in_sizes, int n_in,
                              void* d_out, int out_size, void* d_ws, size_t ws_size,
                              hipStream_t stream)
{
    const float* x       = (const float*)d_in[0];  // (1024, 512)
    const float* logits1 = (const float*)d_in[1];  // (256, 2)
    const float* u1      = (const float*)d_in[2];  // (256, 2)
    const float* logits2 = (const float*)d_in[3];  // (512, 2)
    const float* u2      = (const float*)d_in[4];  // (512, 2)
    const int*   mask1   = (const int*)d_in[5];    // (256, 512)
    const int*   mask2   = (const int*)d_in[6];    // (512, 256)
    float* out = (float*)d_out;                    // (1024, 512) f32

    char* ws = (char*)d_ws;
    uint32_t* xh   = (uint32_t*)(ws);                                    // 1 MB
    uint4*    n1   = (uint4*)(ws + (1 << 20));                           // 256 KB
    uint4*    n2   = (uint4*)(ws + (1 << 20) + (256 << 10));             // 256 KB
    uint16_t* sgn1 = (uint16_t*)(ws + (1 << 20) + (512 << 10));          // 512 B
    uint16_t* sgn2 = (uint16_t*)(ws + (1 << 20) + (512 << 10) + 4096);   // 1 KB
    uint32_t* hh   = (uint32_t*)(ws + (1 << 20) + (512 << 10) + 8192);   // 512 KB: h f16 [1024][256]

    // 1) prep: 262144 + 16384 + 16384 threads = 1152 blocks
    prep_kernel<<<1152, 256, 0, stream>>>(x, logits1, u1, logits2, u2,
                                          mask1, mask2, xh, n1, n2, sgn1, sgn2);

    // 2) layer 1: J=512 (JW=64), OD=256, R=2. Grid = 4 ot * 128 btiles = 512 (2/CU).
    layer_kernel<64, 256, 2, false><<<512, 256, 0, stream>>>(xh, n1, sgn1, (void*)hh);

    // 3) layer 2: J=256 (JW=32), OD=512, R=4. Grid = 8 ot * 64 btiles = 512 (2/CU).
    layer_kernel<32, 512, 4, true><<<512, 256, 0, stream>>>(hh, n2, sgn2, (void*)out);
}